// Round 8
// baseline (419.277 us; speedup 1.0000x reference)
//
#include <hip/hip_runtime.h>

#define NN 30000
#define NE 300000
#define D_IN 256
#define D_H 128
#define D_OUT 64
#define NL 6

typedef unsigned short ushort_t;
typedef unsigned int uint_t;
typedef __attribute__((ext_vector_type(8))) short sh8;
typedef __attribute__((ext_vector_type(4))) float f4;

// fp32 -> bf16 round-to-nearest-even
static __device__ __forceinline__ ushort_t f2bf(float f) {
    uint_t u = __float_as_uint(f);
    u = (u + 0x7FFFu + ((u >> 16) & 1u)) >> 16;
    return (ushort_t)u;
}

// ---------------------------------------------------------------------------
__global__ void degree_kernel(const int* __restrict__ src, const int* __restrict__ dst,
                              int* __restrict__ outdeg, int* __restrict__ indeg) {
    int e = blockIdx.x * blockDim.x + threadIdx.x;
    if (e < NE) {
        atomicAdd(&outdeg[src[e]], 1);
        atomicAdd(&indeg[dst[e]], 1);
    }
}

__global__ void rsqrt_kernel(const int* __restrict__ deg, float* __restrict__ inv, int n) {
    int i = blockIdx.x * blockDim.x + threadIdx.x;
    if (i < n) {
        float d = (float)deg[i];
        inv[i] = rsqrtf(d < 1.0f ? 1.0f : d);
    }
}

// exclusive prefix scan of deg[NN] -> ptr[NN+1]
__global__ __launch_bounds__(1024) void scan_kernel(const int* __restrict__ deg,
                                                    int* __restrict__ ptr) {
    __shared__ int wsum[16];
    __shared__ int chunk_base;
    if (threadIdx.x == 0) chunk_base = 0;
    __syncthreads();
    const int lane = threadIdx.x & 63;
    const int wid = threadIdx.x >> 6;
    for (int base = 0; base < NN; base += 1024) {
        int i = base + threadIdx.x;
        int v = (i < NN) ? deg[i] : 0;
        int s = v;
#pragma unroll
        for (int off = 1; off < 64; off <<= 1) {
            int t = __shfl_up(s, off, 64);
            if (lane >= off) s += t;
        }
        if (lane == 63) wsum[wid] = s;
        __syncthreads();
        if (wid == 0 && lane < 16) {
            int ws = wsum[lane];
#pragma unroll
            for (int off = 1; off < 16; off <<= 1) {
                int t = __shfl_up(ws, off, 64);
                if (lane >= off) ws += t;
            }
            wsum[lane] = ws;
        }
        __syncthreads();
        int cb = chunk_base;
        int woff = (wid > 0) ? wsum[wid - 1] : 0;
        if (i < NN) ptr[i] = cb + woff + s - v;
        int total = wsum[15];
        __syncthreads();
        if (threadIdx.x == 0) chunk_base = cb + total;
        __syncthreads();
    }
    if (threadIdx.x == 0) ptr[NN] = chunk_base;
}

// stage 1: counting-sort edges by src -> es[(src-grouped)] = (src, dst)
__global__ void fill1_kernel(const int* __restrict__ src, const int* __restrict__ dst,
                             const int* __restrict__ src_ptr, int* __restrict__ scur,
                             int2* __restrict__ es) {
    int e = blockIdx.x * blockDim.x + threadIdx.x;
    if (e < NE) {
        int s = src[e];
        int pos = atomicAdd(&scur[s], 1);
        es[src_ptr[s] + pos] = make_int2(s, dst[e]);
    }
}

// stage 2: scan src-sorted edges in index order -> dst-CSR col (approx src-asc)
__global__ void fill2_kernel(const int2* __restrict__ es,
                             const int* __restrict__ row_ptr, int* __restrict__ cursor,
                             int* __restrict__ col) {
    int i = blockIdx.x * blockDim.x + threadIdx.x;
    if (i < NE) {
        int2 e = es[i];
        int pos = atomicAdd(&cursor[e.y], 1);
        col[row_ptr[e.y] + pos] = e.x;
    }
}

// ---------------------------------------------------------------------------
// feats fp32 -> bf16 (flat)
__global__ void featconv_kernel(const float* __restrict__ F, ushort_t* __restrict__ Fb) {
    int i = blockIdx.x * blockDim.x + threadIdx.x;   // over NN*256/8
    if (i >= NN * D_IN / 8) return;
    float4 a = *(const float4*)(F + (size_t)i * 8);
    float4 b = *(const float4*)(F + (size_t)i * 8 + 4);
    uint4 o;
    o.x = (uint_t)f2bf(a.x) | ((uint_t)f2bf(a.y) << 16);
    o.y = (uint_t)f2bf(a.z) | ((uint_t)f2bf(a.w) << 16);
    o.z = (uint_t)f2bf(b.x) | ((uint_t)f2bf(b.y) << 16);
    o.w = (uint_t)f2bf(b.z) | ((uint_t)f2bf(b.w) << 16);
    *(uint4*)(Fb + (size_t)i * 8) = o;
}

// p fp32 [NN,64] -> bf16
__global__ void pconv_kernel(const float* __restrict__ P, ushort_t* __restrict__ Pb) {
    int i = blockIdx.x * blockDim.x + threadIdx.x;   // over NN*64/8
    if (i >= NN * D_OUT / 8) return;
    float4 a = *(const float4*)(P + (size_t)i * 8);
    float4 b = *(const float4*)(P + (size_t)i * 8 + 4);
    uint4 o;
    o.x = (uint_t)f2bf(a.x) | ((uint_t)f2bf(a.y) << 16);
    o.y = (uint_t)f2bf(a.z) | ((uint_t)f2bf(a.w) << 16);
    o.z = (uint_t)f2bf(b.x) | ((uint_t)f2bf(b.y) << 16);
    o.w = (uint_t)f2bf(b.z) | ((uint_t)f2bf(b.w) << 16);
    *(uint4*)(Pb + (size_t)i * 8) = o;
}

// ---------------------------------------------------------------------------
// Pack all weights into MFMA B-fragment order, bf16.
// ---------------------------------------------------------------------------
__global__ void packw_kernel(const float* __restrict__ W0,
                             const float* __restrict__ Wh,
                             const float* __restrict__ Wout,
                             ushort_t* __restrict__ W0p,
                             ushort_t* __restrict__ Whp,
                             ushort_t* __restrict__ Woutp) {
    int g = blockIdx.x * blockDim.x + threadIdx.x;
    int frag = g >> 6;
    int lane = g & 63;
    if (frag >= 368) return;
    const float* srcw;
    ushort_t* dstp;
    int fl, KF, M;
    if (frag < 64) {                     // W0
        fl = frag; KF = 8; M = 128;
        srcw = W0;
        dstp = W0p;
    } else if (frag < 64 + 192) {        // Wh
        int f2 = frag - 64;
        int l = f2 / 32; fl = f2 % 32; KF = 4; M = 128;
        srcw = Wh + (size_t)l * D_H * D_H;
        dstp = Whp + (size_t)l * 32 * 512;
    } else {                             // Wout blocks
        int f2 = frag - 256;
        int l = f2 / 16; fl = f2 % 16; KF = 4; M = 64;
        srcw = Wout + (size_t)l * D_H * D_OUT;
        dstp = Woutp + (size_t)l * 16 * 512;
    }
    int ct = fl / KF;
    int kt = fl % KF;
    int krow = kt * 32 + (lane >> 4) * 8;
    int cidx = ct * 16 + (lane & 15);
    ushort_t tmp[8];
#pragma unroll
    for (int j = 0; j < 8; j++)
        tmp[j] = f2bf(srcw[(size_t)(krow + j) * M + cidx]);
    uint4 o;
    o.x = (uint_t)tmp[0] | ((uint_t)tmp[1] << 16);
    o.y = (uint_t)tmp[2] | ((uint_t)tmp[3] << 16);
    o.z = (uint_t)tmp[4] | ((uint_t)tmp[5] << 16);
    o.w = (uint_t)tmp[6] | ((uint_t)tmp[7] << 16);
    *(uint4*)(dstp + (size_t)fl * 512 + lane * 8) = o;
}

// ---------------------------------------------------------------------------
// MFMA GEMM (bf16 in, no LDS) — unchanged from R6.
// ---------------------------------------------------------------------------
template <int KF, bool HAS_T, bool HAS_P>
__global__ __launch_bounds__(256) void gemm_mfma(
    const ushort_t* __restrict__ Xb,
    const ushort_t* __restrict__ W1p,
    const ushort_t* __restrict__ W2p,
    const float* __restrict__ scale,
    ushort_t* __restrict__ Tb,
    float* __restrict__ P,
    int nrows)
{
    constexpr int K = KF * 32;
    const int lane = threadIdx.x & 63;
    const int w = threadIdx.x >> 6;
    const int rg = w >> 1;
    const int cgrp = w & 1;
    const int row0 = blockIdx.x * 32 + rg * 16;

    int arow = row0 + (lane & 15);
    if (arow >= nrows) arow = nrows - 1;
    const ushort_t* xr = Xb + (size_t)arow * K + ((lane >> 4) * 8);
    sh8 a[KF];
#pragma unroll
    for (int kt = 0; kt < KF; kt++)
        a[kt] = *(const sh8*)(xr + kt * 32);

    const int crow0 = row0 + (lane >> 4) * 4;

    if (HAS_T) {
        float s[4];
#pragma unroll
        for (int r = 0; r < 4; r++) {
            int rw = crow0 + r;
            s[r] = scale[rw < nrows ? rw : nrows - 1];
        }
#pragma unroll
        for (int i = 0; i < 4; i++) {
            int ct = cgrp * 4 + i;
            f4 acc = {0.f, 0.f, 0.f, 0.f};
            const ushort_t* wp = W1p + ((size_t)(ct * KF) << 9) + lane * 8;
#pragma unroll
            for (int kt = 0; kt < KF; kt++)
                acc = __builtin_amdgcn_mfma_f32_16x16x32_bf16(
                    a[kt], *(const sh8*)(wp + ((size_t)kt << 9)), acc, 0, 0, 0);
            int colb = ct * 16 + (lane & 15);
#pragma unroll
            for (int r = 0; r < 4; r++) {
                int rw = crow0 + r;
                if (rw < nrows)
                    Tb[(size_t)rw * 128 + colb] = f2bf(acc[r] * s[r]);
            }
        }
    }
    if (HAS_P) {
#pragma unroll
        for (int i = 0; i < 2; i++) {
            int ct = cgrp * 2 + i;
            f4 acc = {0.f, 0.f, 0.f, 0.f};
            const ushort_t* wp = W2p + ((size_t)(ct * KF) << 9) + lane * 8;
#pragma unroll
            for (int kt = 0; kt < KF; kt++)
                acc = __builtin_amdgcn_mfma_f32_16x16x32_bf16(
                    a[kt], *(const sh8*)(wp + ((size_t)kt << 9)), acc, 0, 0, 0);
            int colb = ct * 16 + (lane & 15);
#pragma unroll
            for (int r = 0; r < 4; r++) {
                int rw = crow0 + r;
                if (rw < nrows) {
                    float* pp = P + (size_t)rw * 64 + colb;
                    *pp += acc[r];
                }
            }
        }
    }
}

// ---------------------------------------------------------------------------
// bf16 CSR gather (D=128), 4x-unrolled:
//   Yb[node,0:128] = bf16(relu( sum Tb[col[j],:] * scale + bias ))
// ---------------------------------------------------------------------------
__global__ __launch_bounds__(256) void gather_bf16_kernel(
    const ushort_t* __restrict__ Tb,
    const int* __restrict__ row_ptr,
    const int* __restrict__ col,
    const float* __restrict__ scale,
    const float* __restrict__ bias,
    ushort_t* __restrict__ Yb) {
    int idx = blockIdx.x * blockDim.x + threadIdx.x;
    int node = idx >> 4;
    int q = idx & 15;
    if (node >= NN) return;
    int beg = row_ptr[node];
    int end = row_ptr[node + 1];
    const uint_t* T32 = (const uint_t*)Tb;   // row = 64 uints
    float acc[8];
#pragma unroll
    for (int i = 0; i < 8; i++) acc[i] = 0.f;

    int j = beg;
    for (; j + 3 < end; j += 4) {
        int c0 = col[j], c1 = col[j + 1], c2 = col[j + 2], c3 = col[j + 3];
        uint4 u0 = *(const uint4*)(T32 + (size_t)c0 * 64 + q * 4);
        uint4 u1 = *(const uint4*)(T32 + (size_t)c1 * 64 + q * 4);
        uint4 u2 = *(const uint4*)(T32 + (size_t)c2 * 64 + q * 4);
        uint4 u3 = *(const uint4*)(T32 + (size_t)c3 * 64 + q * 4);
        uint_t w0[4] = {u0.x, u0.y, u0.z, u0.w};
        uint_t w1[4] = {u1.x, u1.y, u1.z, u1.w};
        uint_t w2[4] = {u2.x, u2.y, u2.z, u2.w};
        uint_t w3[4] = {u3.x, u3.y, u3.z, u3.w};
#pragma unroll
        for (int i = 0; i < 4; i++) {
            acc[2 * i] += (__uint_as_float(w0[i] << 16) + __uint_as_float(w1[i] << 16))
                        + (__uint_as_float(w2[i] << 16) + __uint_as_float(w3[i] << 16));
            acc[2 * i + 1] += (__uint_as_float(w0[i] & 0xFFFF0000u) + __uint_as_float(w1[i] & 0xFFFF0000u))
                            + (__uint_as_float(w2[i] & 0xFFFF0000u) + __uint_as_float(w3[i] & 0xFFFF0000u));
        }
    }
    for (; j < end; j++) {
        int c0 = col[j];
        uint4 u0 = *(const uint4*)(T32 + (size_t)c0 * 64 + q * 4);
        uint_t w0[4] = {u0.x, u0.y, u0.z, u0.w};
#pragma unroll
        for (int i = 0; i < 4; i++) {
            acc[2 * i]     += __uint_as_float(w0[i] << 16);
            acc[2 * i + 1] += __uint_as_float(w0[i] & 0xFFFF0000u);
        }
    }

    float s = scale[node];
    float h[8];
#pragma unroll
    for (int i = 0; i < 8; i++)
        h[i] = fmaxf(fmaf(acc[i], s, bias[q * 8 + i]), 0.f);
    uint4 o;
    o.x = (uint_t)f2bf(h[0]) | ((uint_t)f2bf(h[1]) << 16);
    o.y = (uint_t)f2bf(h[2]) | ((uint_t)f2bf(h[3]) << 16);
    o.z = (uint_t)f2bf(h[4]) | ((uint_t)f2bf(h[5]) << 16);
    o.w = (uint_t)f2bf(h[6]) | ((uint_t)f2bf(h[7]) << 16);
    *(uint4*)(Yb + (size_t)node * 128 + q * 8) = o;
}

// bf16 final gather (D=64): out[node,:] = sum Pb[col[j],:] + bout   (fp32 out)
__global__ __launch_bounds__(256) void gather_out_kernel(
    const ushort_t* __restrict__ Pb,
    const int* __restrict__ row_ptr,
    const int* __restrict__ col,
    const float* __restrict__ bias,
    float* __restrict__ Y) {
    int idx = blockIdx.x * blockDim.x + threadIdx.x;
    int node = idx >> 3;
    int q = idx & 7;
    if (node >= NN) return;
    int beg = row_ptr[node];
    int end = row_ptr[node + 1];
    const uint_t* P32 = (const uint_t*)Pb;   // row = 32 uints
    float acc[8];
#pragma unroll
    for (int i = 0; i < 8; i++) acc[i] = 0.f;

    int j = beg;
    for (; j + 3 < end; j += 4) {
        int c0 = col[j], c1 = col[j + 1], c2 = col[j + 2], c3 = col[j + 3];
        uint4 u0 = *(const uint4*)(P32 + (size_t)c0 * 32 + q * 4);
        uint4 u1 = *(const uint4*)(P32 + (size_t)c1 * 32 + q * 4);
        uint4 u2 = *(const uint4*)(P32 + (size_t)c2 * 32 + q * 4);
        uint4 u3 = *(const uint4*)(P32 + (size_t)c3 * 32 + q * 4);
        uint_t w0[4] = {u0.x, u0.y, u0.z, u0.w};
        uint_t w1[4] = {u1.x, u1.y, u1.z, u1.w};
        uint_t w2[4] = {u2.x, u2.y, u2.z, u2.w};
        uint_t w3[4] = {u3.x, u3.y, u3.z, u3.w};
#pragma unroll
        for (int i = 0; i < 4; i++) {
            acc[2 * i] += (__uint_as_float(w0[i] << 16) + __uint_as_float(w1[i] << 16))
                        + (__uint_as_float(w2[i] << 16) + __uint_as_float(w3[i] << 16));
            acc[2 * i + 1] += (__uint_as_float(w0[i] & 0xFFFF0000u) + __uint_as_float(w1[i] & 0xFFFF0000u))
                            + (__uint_as_float(w2[i] & 0xFFFF0000u) + __uint_as_float(w3[i] & 0xFFFF0000u));
        }
    }
    for (; j < end; j++) {
        int c0 = col[j];
        uint4 u0 = *(const uint4*)(P32 + (size_t)c0 * 32 + q * 4);
        uint_t w0[4] = {u0.x, u0.y, u0.z, u0.w};
#pragma unroll
        for (int i = 0; i < 4; i++) {
            acc[2 * i]     += __uint_as_float(w0[i] << 16);
            acc[2 * i + 1] += __uint_as_float(w0[i] & 0xFFFF0000u);
        }
    }

    float4 o0, o1;
    o0.x = acc[0] + bias[q * 8 + 0];
    o0.y = acc[1] + bias[q * 8 + 1];
    o0.z = acc[2] + bias[q * 8 + 2];
    o0.w = acc[3] + bias[q * 8 + 3];
    o1.x = acc[4] + bias[q * 8 + 4];
    o1.y = acc[5] + bias[q * 8 + 5];
    o1.z = acc[6] + bias[q * 8 + 6];
    o1.w = acc[7] + bias[q * 8 + 7];
    *(float4*)(Y + (size_t)node * 64 + q * 8) = o0;
    *(float4*)(Y + (size_t)node * 64 + q * 8 + 4) = o1;
}

// ---------------------------------------------------------------------------
extern "C" void kernel_launch(void* const* d_in, const int* in_sizes, int n_in,
                              void* d_out, int out_size, void* d_ws, size_t ws_size,
                              hipStream_t stream) {
    const float* feats = (const float*)d_in[0];
    const int*   src   = (const int*)d_in[1];
    const int*   dst   = (const int*)d_in[2];
    const float* W0    = (const float*)d_in[3];
    const float* b0    = (const float*)d_in[4];
    const float* Wh    = (const float*)d_in[5];
    const float* bh    = (const float*)d_in[6];
    const float* Wout  = (const float*)d_in[7];
    const float* bout  = (const float*)d_in[8];
    float* out = (float*)d_out;

    float* ws      = (float*)d_ws;
    float* inv_out = ws;                              // NN
    float* inv_in  = ws + NN;                         // NN
    float* p       = ws + 2 * NN;                     // NN*64 fp32
    ushort_t* tb   = (ushort_t*)(p + (size_t)NN * 64);      // NN*128 bf16
    ushort_t* ha   = tb + (size_t)NN * 128;           // NN*128 bf16
    ushort_t* hb   = ha + (size_t)NN * 128;           // NN*128 bf16
    ushort_t* fb   = hb + (size_t)NN * 128;           // NN*256 bf16
    ushort_t* pb   = fb + (size_t)NN * 256;           // NN*64 bf16
    ushort_t* w0p  = pb + (size_t)NN * 64;            // 64*512
    ushort_t* whp  = w0p + 64 * 512;                  // 192*512
    ushort_t* wop  = whp + 192 * 512;                 // 112*512
    int* ibase     = (int*)(wop + 112 * 512);
    int* outdeg_i  = ibase;                           // NN
    int* indeg_i   = ibase + NN;                      // NN
    int* row_ptr   = ibase + 2 * NN;                  // NN+1
    int* src_ptr   = row_ptr + NN + 1;                // NN+1
    int* cursor    = src_ptr + NN + 1;                // NN
    int* scur      = cursor + NN;                     // NN
    int* col       = scur + NN;                       // NE
    int2* es       = (int2*)(col + NE);               // NE int2

    const int B = 256;
    const int gemm_blocks = (NN + 31) / 32;           // 938
    const int gather_blocks = (NN * 16 + B - 1) / B;
    const int gout_blocks = (NN * 8 + B - 1) / B;

    // ---- CSR build (src-sorted adjacency) + norms + conversions + packing ----
    hipMemsetAsync(outdeg_i, 0, 2 * NN * sizeof(int), stream);   // outdeg+indeg
    hipMemsetAsync(cursor, 0, 2 * NN * sizeof(int), stream);     // cursor+scur
    hipMemsetAsync(p, 0, (size_t)NN * D_OUT * sizeof(float), stream);
    degree_kernel<<<(NE + B - 1) / B, B, 0, stream>>>(src, dst, outdeg_i, indeg_i);
    rsqrt_kernel<<<(2 * NN + B - 1) / B, B, 0, stream>>>(outdeg_i, inv_out, 2 * NN);
    scan_kernel<<<1, 1024, 0, stream>>>(indeg_i, row_ptr);
    scan_kernel<<<1, 1024, 0, stream>>>(outdeg_i, src_ptr);
    fill1_kernel<<<(NE + B - 1) / B, B, 0, stream>>>(src, dst, src_ptr, scur, es);
    fill2_kernel<<<(NE + B - 1) / B, B, 0, stream>>>(es, row_ptr, cursor, col);
    featconv_kernel<<<(NN * D_IN / 8 + B - 1) / B, B, 0, stream>>>(feats, fb);
    packw_kernel<<<(368 * 64 + B - 1) / B, B, 0, stream>>>(W0, Wh, Wout, w0p, whp, wop);

    // ---- layer 0 ----
    gemm_mfma<8, true, false><<<gemm_blocks, 256, 0, stream>>>(
        fb, w0p, nullptr, inv_out, tb, nullptr, NN);
    gather_bf16_kernel<<<gather_blocks, B, 0, stream>>>(
        tb, row_ptr, col, inv_in, b0, ha);

    // ---- layers 1..6 fused with p += h_l @ Wout_l ----
    ushort_t* hcur = ha;
    ushort_t* hnext = hb;
    for (int l = 0; l < NL; l++) {
        gemm_mfma<4, true, true><<<gemm_blocks, 256, 0, stream>>>(
            hcur, whp + (size_t)l * 32 * 512, wop + (size_t)l * 16 * 512,
            inv_out, tb, p, NN);
        gather_bf16_kernel<<<gather_blocks, B, 0, stream>>>(
            tb, row_ptr, col, inv_in, bh + (size_t)l * D_H, hnext);
        ushort_t* tmp = hcur; hcur = hnext; hnext = tmp;
    }

    // ---- tail: p += h_6 @ Wout_6 ----
    gemm_mfma<4, false, true><<<gemm_blocks, 256, 0, stream>>>(
        hcur, nullptr, wop + (size_t)NL * 16 * 512, nullptr, nullptr, p, NN);

    // ---- out = gather(bf16(p)) + bout ----
    pconv_kernel<<<(NN * D_OUT / 8 + B - 1) / B, B, 0, stream>>>(p, pb);
    gather_out_kernel<<<gout_blocks, B, 0, stream>>>(pb, row_ptr, col, bout, out);
}